// Round 4
// baseline (87.134 us; speedup 1.0000x reference)
//
#include <hip/hip_runtime.h>
#include <stdint.h>
#include <math.h>

// Problem constants
#define NV 32      // num_vari (groups)
#define NB 4096    // batch
#define NK 256     // 2*dim_per_vari (contraction)
#define NO 256     // dim_to (output features)
#define BM 64      // batch rows per block

typedef __bf16 bf16x8 __attribute__((ext_vector_type(8)));
typedef float  f32x4  __attribute__((ext_vector_type(4)));

__device__ __forceinline__ f32x4 mfma16(bf16x8 a, bf16x8 b, f32x4 c) {
    return __builtin_amdgcn_mfma_f32_16x16x32_bf16(a, b, c, 0, 0, 0);
}

__device__ __forceinline__ float softplus_f(float z) {
    // stable: max(z,0) + log(1+exp(-|z|)); fast-math err ~1e-3 << 1.055 threshold
    return fmaxf(z, 0.0f) + __logf(1.0f + __expf(-fabsf(z)));
}

__device__ __forceinline__ void gload_lds16(const void* g, void* l) {
    // async global->LDS, 16 B/lane; LDS dest = wave-uniform base + lane*16
    __builtin_amdgcn_global_load_lds((const __attribute__((address_space(1))) uint32_t*)g,
                                     (__attribute__((address_space(3))) uint32_t*)l,
                                     16, 0, 0);
}

// ---------------------------------------------------------------------------
// prep: W[v][k][o] fp32  ->  Wt[v][o][k] bf16  (transpose + convert, 4 MB)
__global__ __launch_bounds__(256)
void prep_wt_kernel(const float* __restrict__ w, __bf16* __restrict__ wt) {
    const int id = blockIdx.x * 256 + threadIdx.x;   // 32*256*32 = 262144
    const int o  = id & 255;
    const int kc = (id >> 8) & 31;    // 8-k chunk
    const int v  = id >> 13;
    const float* src = w + ((size_t)v * NK + (size_t)kc * 8) * NO + o;
    bf16x8 r;
#pragma unroll
    for (int j = 0; j < 8; ++j) r[j] = (__bf16)src[(size_t)j * NO];
    *(bf16x8*)(wt + ((size_t)v * NO + o) * NK + kc * 8) = r;
}

// ---------------------------------------------------------------------------
// main: out[v][b][o] = softplus( x[v][b][:] . Wt[v][o][:] + 256*bias[v][o] )
//
// Structure: x-tile -> LDS via global_load_lds (async DMA, fp32, no VGPRs),
// 16B-chunk XOR swizzle pc = cl ^ (row&7) (linear dest + inverse-swizzled
// global source + swizzled read). ONE vmcnt drain + ONE barrier per block.
// W streamed from L2 into registers at prefetch depth 2. cvt fp32->bf16 at
// fragment-read time.
__global__ __launch_bounds__(512, 2)
void mv_dense_kernel(const float* __restrict__ x, const __bf16* __restrict__ wt,
                     const float* __restrict__ bias, float* __restrict__ out) {
    // As[row][k] fp32, 64 rows x 1024 B. Chunk = 16 B (4 floats), 64/row.
    // phys chunk pc of logical chunk cl in row r:  pc = cl ^ (r & 7)
    __shared__ float As[BM * NK];   // 64 KB

    const int t    = threadIdx.x;
    const int w    = t >> 6;      // wave 0..7 -> o-columns [w*32, w*32+32)
    const int lane = t & 63;
    const int lr   = lane & 15;
    const int lg   = lane >> 4;

    // XCD-chunked swizzle: 2048 = 8 XCD x 256; same-v blocks share one L2
    const int bid = blockIdx.x;
    const int bsw = (bid & 7) * 256 + (bid >> 3);
    const int v   = bsw >> 6;
    const int mb  = bsw & 63;

    const float*  xg = x    + ((size_t)v * NB + (size_t)mb * BM) * NK;
    const __bf16* wg = wt   + (size_t)v * NO * NK;
    const float*  bg = bias + (size_t)v * NO;
    float*        og = out  + ((size_t)v * NB + (size_t)mb * BM) * NO;

    // ---- stage x: 8 async gload_lds per thread; wave fills phys row p*8+w ----
    // phys chunk in row = lane; logical chunk cl = lane ^ (r&7) = lane ^ w
    const int srco = (lane ^ w) * 4;   // float offset of this lane's source chunk
#pragma unroll
    for (int p = 0; p < 8; ++p) {
        const int r = p * 8 + w;
        gload_lds16(xg + (size_t)r * NK + srco,
                    (void*)((char*)As + (size_t)r * 1024));
    }

    // ---- W L2-stream, depth-2 prologue (registers) ----
    const __bf16* wb0 = wg + (size_t)(w * 32 + lr) * NK + lg * 8;   // j=0 frag ptr
    const __bf16* wb1 = wb0 + (size_t)16 * NK;                      // j=1
    bf16x8 c00 = *(const bf16x8*)wb0;
    bf16x8 c10 = *(const bf16x8*)wb1;
    bf16x8 c01 = *(const bf16x8*)(wb0 + 32);
    bf16x8 c11 = *(const bf16x8*)(wb1 + 32);

    // bias, pre-scaled by 256, laid out per C-fragment (4 consecutive o/lane)
    f32x4 bb[2];
#pragma unroll
    for (int j = 0; j < 2; ++j) {
        f32x4 bv = *(const f32x4*)(bg + w * 32 + j * 16 + lg * 4);
#pragma unroll
        for (int r = 0; r < 4; ++r) bb[j][r] = 256.0f * bv[r];
    }

    __syncthreads();   // the ONLY barrier (drains gload_lds queue once)

    f32x4 acc[4][2];
#pragma unroll
    for (int i = 0; i < 4; ++i)
#pragma unroll
        for (int j = 0; j < 2; ++j) {
            f32x4 z4 = {0.f, 0.f, 0.f, 0.f};
            acc[i][j] = z4;
        }

    // ---- K loop: ds_read fp32 frags + cvt + depth-2 L2 W stream + MFMA ----
#pragma unroll
    for (int kk = 0; kk < 8; ++kk) {
        bf16x8 n0 = c01, n1 = c11;
        if (kk < 6) {   // depth-2 register prefetch from L2
            n0 = *(const bf16x8*)(wb0 + (kk + 2) * 32);
            n1 = *(const bf16x8*)(wb1 + (kk + 2) * 32);
        }
        // A fragments: row R = i*16+lr, logical unit u = kk*4+lg (8 fp32)
        bf16x8 afr[4];
#pragma unroll
        for (int i = 0; i < 4; ++i) {
            const int R   = i * 16 + lr;
            const int pcA = (2 * (kk * 4 + lg)) ^ (R & 7);   // logical chunk 2u
            const int pcB = pcA ^ 1;                          // logical chunk 2u+1
            f32x4 lo = *(const f32x4*)((const char*)As + (size_t)R * 1024 + pcA * 16);
            f32x4 hi = *(const f32x4*)((const char*)As + (size_t)R * 1024 + pcB * 16);
            bf16x8 a;
#pragma unroll
            for (int e = 0; e < 4; ++e) { a[e] = (__bf16)lo[e]; a[e + 4] = (__bf16)hi[e]; }
            afr[i] = a;
        }
#pragma unroll
        for (int i = 0; i < 4; ++i) {
            // A-operand := Wt frag, B-operand := x frag -> D[o][batch]
            acc[i][0] = mfma16(c00, afr[i], acc[i][0]);
            acc[i][1] = mfma16(c10, afr[i], acc[i][1]);
        }
        // roll the pipeline
        c00 = c01; c10 = c11; c01 = n0; c11 = n1;
    }

    // ---- epilogue: batch = i*16 + lr, o = w*32 + j*16 + lg*4 + r ----
#pragma unroll
    for (int i = 0; i < 4; ++i) {
        const size_t rowbase = (size_t)(i * 16 + lr) * NO;
#pragma unroll
        for (int j = 0; j < 2; ++j) {
            f32x4 res;
#pragma unroll
            for (int r = 0; r < 4; ++r)
                res[r] = softplus_f(acc[i][j][r] + bb[j][r]);
            *(f32x4*)(og + rowbase + w * 32 + j * 16 + lg * 4) = res;
        }
    }
}

extern "C" void kernel_launch(void* const* d_in, const int* in_sizes, int n_in,
                              void* d_out, int out_size, void* d_ws, size_t ws_size,
                              hipStream_t stream) {
    const float* x  = (const float*)d_in[0];
    const float* w  = (const float*)d_in[1];
    const float* b  = (const float*)d_in[2];
    float* out      = (float*)d_out;
    __bf16* wt      = (__bf16*)d_ws;   // 32*256*256*2 B = 4 MB scratch

    // 1) transpose+convert W -> Wt bf16
    hipLaunchKernelGGL(prep_wt_kernel, dim3(1024), dim3(256), 0, stream, w, wt);
    // 2) grouped GEMM + bias + softplus
    hipLaunchKernelGGL(mv_dense_kernel, dim3(NV * (NB / BM)), dim3(512), 0, stream,
                       x, wt, b, out);
}